// Round 8
// baseline (2757.958 us; speedup 1.0000x reference)
//
#include <hip/hip_runtime.h>
#include <hip/hip_bf16.h>

typedef __hip_bfloat16 hbf16;
using bf16x8 = __attribute__((ext_vector_type(8))) __bf16;
using f32x4 = __attribute__((ext_vector_type(4))) float;

// GPT-2 small: L=12 H=12 D=768 V=50257 T=1024 B=2, HD=64
constexpr int Lc = 12, Hc = 12, Dc = 768, Vc = 50257, Tc = 1024, Bc = 2, HDc = 64;
constexpr int Mc = Bc * Tc;  // 2048 rows
constexpr int Vpad = 50304;  // 393*128, zero-padded vocab

// transposed-weight slot sizes (elements)
constexpr size_t SZ_Q = (size_t)3 * Dc * Dc;   // [2304][768]
constexpr size_t SZ_P = (size_t)Dc * Dc;       // [768][768]
constexpr size_t SZ_F = (size_t)4 * Dc * Dc;   // [3072][768]
constexpr size_t SZ_FP = (size_t)4 * Dc * Dc;  // [768][3072]
constexpr size_t SZL = SZ_Q + SZ_P + SZ_F + SZ_FP;

#define GLD16(gp, lp)                                               \
    __builtin_amdgcn_global_load_lds(                               \
        (__attribute__((address_space(1))) void*)(void*)(gp),       \
        (__attribute__((address_space(3))) void*)(void*)(lp), 16, 0, 0)

// ---------------- embedding: h = wte[x] + wpe[t] (f32) ----------------
__global__ void embed_kernel(const int* __restrict__ x, const float* __restrict__ wte,
                             const float* __restrict__ wpe, float* __restrict__ h) {
    int i = blockIdx.x * blockDim.x + threadIdx.x;
    if (i >= Mc * Dc) return;
    int m = i / Dc, d = i - m * Dc;
    int t = m % Tc;
    int tok = x[m];
    h[i] = wte[(size_t)tok * Dc + d] + wpe[(size_t)t * Dc + d];
}

// ---------------- layernorm: one wave per row, shuffle reduce, f32 in -> bf16 out --
__global__ __launch_bounds__(256) void ln_kernel(const float* __restrict__ x,
                                                 const float* __restrict__ w,
                                                 const float* __restrict__ b,
                                                 hbf16* __restrict__ out) {
    int wv = threadIdx.x >> 6, lane = threadIdx.x & 63;
    int row = blockIdx.x * 4 + wv;
    const float4* xr = (const float4*)(x + (size_t)row * Dc);
    float4 v[3];
    float s = 0.f, sq = 0.f;
#pragma unroll
    for (int i = 0; i < 3; i++) {
        v[i] = xr[i * 64 + lane];
        s += v[i].x + v[i].y + v[i].z + v[i].w;
        sq += v[i].x * v[i].x + v[i].y * v[i].y + v[i].z * v[i].z + v[i].w * v[i].w;
    }
#pragma unroll
    for (int o = 32; o > 0; o >>= 1) {
        s += __shfl_xor(s, o, 64);
        sq += __shfl_xor(sq, o, 64);
    }
    float mean = s * (1.f / Dc);
    float var = sq * (1.f / Dc) - mean * mean;
    float rstd = rsqrtf(var + 1e-5f);
#pragma unroll
    for (int i = 0; i < 3; i++) {
        int c = (i * 64 + lane) * 4;
        float4 wv4 = *(const float4*)(w + c);
        float4 bv4 = *(const float4*)(b + c);
        float r0 = (v[i].x - mean) * rstd * wv4.x + bv4.x;
        float r1 = (v[i].y - mean) * rstd * wv4.y + bv4.y;
        float r2 = (v[i].z - mean) * rstd * wv4.z + bv4.z;
        float r3 = (v[i].w - mean) * rstd * wv4.w + bv4.w;
        __bf16 q0 = (__bf16)r0, q1 = (__bf16)r1, q2 = (__bf16)r2, q3 = (__bf16)r3;
        ushort4 u;
        u.x = *(unsigned short*)&q0; u.y = *(unsigned short*)&q1;
        u.z = *(unsigned short*)&q2; u.w = *(unsigned short*)&q3;
        *(ushort4*)(out + (size_t)row * Dc + c) = u;
    }
}

// ---------------- weight transpose, grid (6912, nlayers) ----------------
// blockIdx.y = layer; srcs offset by fixed per-matrix strides, dsts by SZL.
__global__ __launch_bounds__(256) void transpose4_kernel(
    const float* __restrict__ s0, const float* __restrict__ s1,
    const float* __restrict__ s2, const float* __restrict__ s3,
    hbf16* __restrict__ d0, hbf16* __restrict__ d1,
    hbf16* __restrict__ d2, hbf16* __restrict__ d3) {
    int id = blockIdx.x;
    size_t lz = blockIdx.y;
    int bx, by, K, N;
    const float* W;
    hbf16* Wt;
    if (id < 1728)      { int t = id;        bx = t % 72; by = t / 72; K = 768;  N = 2304; W = s0 + lz * SZ_Q;  Wt = d0 + lz * SZL; }
    else if (id < 2304) { int t = id - 1728; bx = t % 24; by = t / 24; K = 768;  N = 768;  W = s1 + lz * SZ_P;  Wt = d1 + lz * SZL; }
    else if (id < 4608) { int t = id - 2304; bx = t % 96; by = t / 96; K = 768;  N = 3072; W = s2 + lz * SZ_F;  Wt = d2 + lz * SZL; }
    else                { int t = id - 4608; bx = t % 24; by = t / 24; K = 3072; N = 768;  W = s3 + lz * SZ_FP; Wt = d3 + lz * SZL; }

    __shared__ float tile[32][33];
    int n0 = bx * 32, k0 = by * 32;
    int tx = threadIdx.x & 31, ty = threadIdx.x >> 5;  // 32x8
#pragma unroll
    for (int i = 0; i < 4; i++) {
        int r = ty + i * 8;
        tile[r][tx] = W[(size_t)(k0 + r) * N + n0 + tx];
    }
    __syncthreads();
#pragma unroll
    for (int i = 0; i < 4; i++) {
        int r = ty + i * 8;
        Wt[(size_t)(n0 + r) * K + k0 + tx] = __float2bfloat16(tile[tx][r]);
    }
}

// ---------------- wte f32 [V][D] -> bf16 [Vpad][D] (zero pad) ----------------
__global__ void convert_wte(const float* __restrict__ wte, hbf16* __restrict__ out) {
    size_t i4 = ((size_t)blockIdx.x * 256 + threadIdx.x) * 4;
    if (i4 >= (size_t)Vpad * Dc) return;
    if (i4 < (size_t)Vc * Dc) {
#pragma unroll
        for (int j = 0; j < 4; j++) out[i4 + j] = __float2bfloat16(wte[i4 + j]);
    } else {
#pragma unroll
        for (int j = 0; j < 4; j++) out[i4 + j] = __float2bfloat16(0.f);
    }
}

// ---------------- MFMA GEMM 128xBN, 2-phase dbuf: C = A @ Bt^T + epilogue ---------
// EPI: 0 = +bias, 1 = +bias +f32 residual, 2 = +bias + tanh-GELU
template <int EPI, bool OUTBF, int BN>
__global__ __launch_bounds__(256) void mm_kernel(const hbf16* __restrict__ A,
                                                 const hbf16* __restrict__ Bt,
                                                 const float* __restrict__ bias,
                                                 const float* __restrict__ resid,
                                                 void* __restrict__ Cout,
                                                 int M, int N, int K) {
    constexpr int NF = BN / 32;  // n-frags per wave
    __shared__ __bf16 As[2][128 * 32];
    __shared__ __bf16 Bs[2][BN * 32];
    int tid = threadIdx.x;
    int l = tid & 63, w = tid >> 6;
    int wr = w >> 1, wc = w & 1;

    // XCD swizzle: hw dispatch order is x-fastest; chunk per XCD, m fastest.
    int gx = gridDim.x, gy = gridDim.y;
    int nwg = gx * gy;  // divisible by 8 for all our launches
    int hwlin = blockIdx.y * gx + blockIdx.x;
    int wk = (hwlin & 7) * (nwg >> 3) + (hwlin >> 3);
    int m0 = (wk % gy) * 128;
    int n0 = (wk / gy) * BN;

    // staging: slot swizzle s' = s ^ (row&3); 256 threads -> 64 rows / issue
    int sr = tid >> 2, sc = tid & 3;
    int scs = (sc ^ (sr & 3)) * 8;
    const hbf16* gA0 = A + (size_t)(m0 + sr) * K + scs;
    const hbf16* gA1 = A + (size_t)(m0 + 64 + sr) * K + scs;
    const hbf16* gB0 = Bt + (size_t)(n0 + sr) * K + scs;
    const hbf16* gB1 = (BN == 128) ? Bt + (size_t)(n0 + 64 + sr) * K + scs : gB0;

    auto stage = [&](int bi, int ko) {
        GLD16(gA0 + ko, &As[bi][tid * 8]);
        GLD16(gA1 + ko, &As[bi][2048 + tid * 8]);
        GLD16(gB0 + ko, &Bs[bi][tid * 8]);
        if constexpr (BN == 128) GLD16(gB1 + ko, &Bs[bi][2048 + tid * 8]);
    };

    int lr = l & 15, lg = l >> 4;
    int ksl = (lg ^ (lr & 3)) * 8;  // swizzled k-slot for frag reads
    int aoff[4], boff[NF];
#pragma unroll
    for (int m = 0; m < 4; m++) aoff[m] = (wr * 64 + m * 16 + lr) * 32 + ksl;
#pragma unroll
    for (int n = 0; n < NF; n++) boff[n] = (wc * (BN / 2) + n * 16 + lr) * 32 + ksl;

    f32x4 acc[4][NF] = {};
    int nk = K / 32;

    stage(0, 0);
    __syncthreads();
    for (int t = 0; t < nk; ++t) {
        int cur = t & 1;
        if (t + 1 < nk) stage(cur ^ 1, (t + 1) * 32);  // prefetch under compute
        bf16x8 af[4], bfr[NF];
#pragma unroll
        for (int m = 0; m < 4; m++) af[m] = *(const bf16x8*)&As[cur][aoff[m]];
#pragma unroll
        for (int n = 0; n < NF; n++) bfr[n] = *(const bf16x8*)&Bs[cur][boff[n]];
#pragma unroll
        for (int m = 0; m < 4; m++)
#pragma unroll
            for (int n = 0; n < NF; n++)
                acc[m][n] = __builtin_amdgcn_mfma_f32_16x16x32_bf16(af[m], bfr[n], acc[m][n], 0, 0, 0);
        __syncthreads();  // drains prefetch (overlapped with MFMA above)
    }

#pragma unroll
    for (int n = 0; n < NF; n++) {
        int col = n0 + wc * (BN / 2) + n * 16 + lr;
        bool cok = col < N;
        float bv = (bias && cok) ? bias[col] : 0.f;
#pragma unroll
        for (int m = 0; m < 4; m++) {
#pragma unroll
            for (int r = 0; r < 4; r++) {
                int row = m0 + wr * 64 + m * 16 + lg * 4 + r;
                if (!cok) continue;
                float v = acc[m][n][r] + bv;
                if (EPI == 1) v += resid[(size_t)row * N + col];
                if (EPI == 2) {
                    float x3 = v * v * v;
                    v = 0.5f * v * (1.f + tanhf(0.7978845608028654f * (v + 0.044715f * x3)));
                }
                if (OUTBF)
                    ((hbf16*)Cout)[(size_t)row * N + col] = __float2bfloat16(v);
                else
                    ((float*)Cout)[(size_t)row * N + col] = v;
            }
        }
    }
}

// ---------------- MFMA GEMM 256x128, 512 threads, 2-phase dbuf (lm_head) ----------
__global__ __launch_bounds__(512) void mm2_kernel(const hbf16* __restrict__ A,
                                                  const hbf16* __restrict__ Bt,
                                                  float* __restrict__ Cout,
                                                  int M, int N, int K) {
    __shared__ __bf16 As[2][256 * 32];  // 2 x 16 KB
    __shared__ __bf16 Bs[2][128 * 32];  // 2 x 8 KB
    int tid = threadIdx.x;
    int l = tid & 63, w = tid >> 6;
    int wr = w >> 1, wc = w & 1;

    // XCD swizzle on hw dispatch order; m fastest within chunk (B-panel L2 reuse)
    int gx = gridDim.x, gy = gridDim.y;  // gy = 8
    int nwg = gx * gy;                   // 3144
    int hwlin = blockIdx.y * gx + blockIdx.x;
    int wk = (hwlin & 7) * (nwg >> 3) + (hwlin >> 3);
    int m0 = (wk & 7) * 256;
    int n0 = (wk >> 3) * 128;

    // staging: sr in [0,128) with 512 threads; A = 2 issues, B = 1
    int sr = tid >> 2, sc = tid & 3;
    int scs = (sc ^ (sr & 3)) * 8;
    const hbf16* gA0 = A + (size_t)(m0 + sr) * K + scs;
    const hbf16* gA1 = A + (size_t)(m0 + 128 + sr) * K + scs;
    const hbf16* gB = Bt + (size_t)(n0 + sr) * K + scs;

    auto stage = [&](int bi, int ko) {
        GLD16(gA0 + ko, &As[bi][tid * 8]);
        GLD16(gA1 + ko, &As[bi][4096 + tid * 8]);
        GLD16(gB + ko, &Bs[bi][tid * 8]);
    };

    int lr = l & 15, lg = l >> 4;
    int ksl = (lg ^ (lr & 3)) * 8;
    int aoff[4], boff[4];
#pragma unroll
    for (int m = 0; m < 4; m++) aoff[m] = (wr * 64 + m * 16 + lr) * 32 + ksl;
#pragma unroll
    for (int n = 0; n < 4; n++) boff[n] = (wc * 64 + n * 16 + lr) * 32 + ksl;

    f32x4 acc[4][4] = {};
    int nk = K / 32;

    stage(0, 0);
    __syncthreads();
    for (int t = 0; t < nk; ++t) {
        int cur = t & 1;
        if (t + 1 < nk) stage(cur ^ 1, (t + 1) * 32);
        bf16x8 af[4], bfr[4];
#pragma unroll
        for (int m = 0; m < 4; m++) af[m] = *(const bf16x8*)&As[cur][aoff[m]];
#pragma unroll
        for (int n = 0; n < 4; n++) bfr[n] = *(const bf16x8*)&Bs[cur][boff[n]];
#pragma unroll
        for (int m = 0; m < 4; m++)
#pragma unroll
            for (int n = 0; n < 4; n++)
                acc[m][n] = __builtin_amdgcn_mfma_f32_16x16x32_bf16(af[m], bfr[n], acc[m][n], 0, 0, 0);
        __syncthreads();
    }

#pragma unroll
    for (int n = 0; n < 4; n++) {
        int col = n0 + wc * 64 + n * 16 + lr;
        if (col >= N) continue;
#pragma unroll
        for (int m = 0; m < 4; m++) {
#pragma unroll
            for (int r = 0; r < 4; r++) {
                int row = m0 + wr * 64 + m * 16 + lg * 4 + r;
                Cout[(size_t)row * N + col] = acc[m][n][r];
            }
        }
    }
}

// ---------------- MFMA flash attention ----------------
__global__ __launch_bounds__(256) void fattn_kernel(const hbf16* __restrict__ qkv,
                                                    hbf16* __restrict__ y) {
    int qt = gridDim.x - 1 - blockIdx.x;  // heavy tiles first
    int h = blockIdx.y, b = blockIdx.z;
    int q0 = qt * 64;
    int tid = threadIdx.x;
    int l = tid & 63, w = tid >> 6;
    int li = l & 15, lg = l >> 4;
    constexpr int RS = 3 * Dc;
    constexpr int PST = 72;
    constexpr int VST = 72;

    __shared__ __bf16 P_lds[4][16 * PST];
    __shared__ __bf16 Vt[64 * VST];

    bf16x8 qf[2];
    {
        const hbf16* qp = qkv + (size_t)(b * Tc + q0 + w * 16 + li) * RS + h * HDc + lg * 8;
        qf[0] = *(const bf16x8*)qp;
        qf[1] = *(const bf16x8*)(qp + 32);
    }

    f32x4 acc_o[4] = {};
    float m_run[4], l_run[4];
#pragma unroll
    for (int r = 0; r < 4; r++) { m_run[r] = -1e30f; l_run[r] = 0.f; }

    for (int jt = 0; jt <= qt; jt++) {
        int j0 = jt * 64;
        {
            int j = tid >> 2;
            int dbase = (tid & 3) * 16;
            const hbf16* vp = qkv + (size_t)(b * Tc + j0 + j) * RS + 2 * Dc + h * HDc + dbase;
            bf16x8 v0 = *(const bf16x8*)vp;
            bf16x8 v1 = *(const bf16x8*)(vp + 8);
#pragma unroll
            for (int i = 0; i < 8; i++) Vt[(dbase + i) * VST + j] = v0[i];
#pragma unroll
            for (int i = 0; i < 8; i++) Vt[(dbase + 8 + i) * VST + j] = v1[i];
        }

        f32x4 s[4] = {};
#pragma unroll
        for (int ks = 0; ks < 2; ks++) {
#pragma unroll
            for (int n = 0; n < 4; n++) {
                const hbf16* kp = qkv + (size_t)(b * Tc + j0 + n * 16 + li) * RS + Dc + h * HDc + ks * 32 + lg * 8;
                bf16x8 kf = *(const bf16x8*)kp;
                s[n] = __builtin_amdgcn_mfma_f32_16x16x32_bf16(qf[ks], kf, s[n], 0, 0, 0);
            }
        }
#pragma unroll
        for (int n = 0; n < 4; n++)
#pragma unroll
            for (int r = 0; r < 4; r++) s[n][r] *= 0.125f;

        if (jt == qt) {
            int qloc = w * 16 + lg * 4;
#pragma unroll
            for (int n = 0; n < 4; n++) {
                int jloc = n * 16 + li;
#pragma unroll
                for (int r = 0; r < 4; r++)
                    if (jloc > qloc + r) s[n][r] = -1e30f;
            }
        }

        float mnew[4], scl[4];
#pragma unroll
        for (int r = 0; r < 4; r++) {
            float mx = fmaxf(fmaxf(s[0][r], s[1][r]), fmaxf(s[2][r], s[3][r]));
#pragma unroll
            for (int msk = 1; msk <= 8; msk <<= 1) mx = fmaxf(mx, __shfl_xor(mx, msk, 64));
            mnew[r] = fmaxf(m_run[r], mx);
            scl[r] = expf(m_run[r] - mnew[r]);
            m_run[r] = mnew[r];
        }
        float rs[4] = {0.f, 0.f, 0.f, 0.f};
#pragma unroll
        for (int n = 0; n < 4; n++)
#pragma unroll
            for (int r = 0; r < 4; r++) {
                float p = expf(s[n][r] - mnew[r]);
                s[n][r] = p;
                rs[r] += p;
            }
#pragma unroll
        for (int r = 0; r < 4; r++) {
#pragma unroll
            for (int msk = 1; msk <= 8; msk <<= 1) rs[r] += __shfl_xor(rs[r], msk, 64);
            l_run[r] = l_run[r] * scl[r] + rs[r];
        }

#pragma unroll
        for (int n = 0; n < 4; n++)
#pragma unroll
            for (int r = 0; r < 4; r++) {
                hbf16 t = __float2bfloat16(s[n][r]);
                P_lds[w][(lg * 4 + r) * PST + n * 16 + li] = *(__bf16*)&t;
            }
        bf16x8 pa0 = *(const bf16x8*)&P_lds[w][li * PST + lg * 8];
        bf16x8 pa1 = *(const bf16x8*)&P_lds[w][li * PST + 32 + lg * 8];

#pragma unroll
        for (int n2 = 0; n2 < 4; n2++)
#pragma unroll
            for (int r = 0; r < 4; r++) acc_o[n2][r] *= scl[r];

        __syncthreads();
#pragma unroll
        for (int n2 = 0; n2 < 4; n2++) {
            bf16x8 vf0 = *(const bf16x8*)&Vt[(n2 * 16 + li) * VST + lg * 8];
            bf16x8 vf1 = *(const bf16x8*)&Vt[(n2 * 16 + li) * VST + 32 + lg * 8];
            acc_o[n2] = __builtin_amdgcn_mfma_f32_16x16x32_bf16(pa0, vf0, acc_o[n2], 0, 0, 0);
            acc_o[n2] = __builtin_amdgcn_mfma_f32_16x16x32_bf16(pa1, vf1, acc_o[n2], 0, 0, 0);
        }
        __syncthreads();
    }

#pragma unroll
    for (int r = 0; r < 4; r++) {
        float rcp = 1.f / l_run[r];
        int row = q0 + w * 16 + lg * 4 + r;
#pragma unroll
        for (int n2 = 0; n2 < 4; n2++)
            y[(size_t)(b * Tc + row) * Dc + h * HDc + n2 * 16 + li] =
                __float2bfloat16(acc_o[n2][r] * rcp);
    }
}

extern "C" void kernel_launch(void* const* d_in, const int* in_sizes, int n_in,
                              void* d_out, int out_size, void* d_ws, size_t ws_size,
                              hipStream_t stream) {
    const int* x = (const int*)d_in[0];
    const float* wte = (const float*)d_in[1];
    const float* wpe = (const float*)d_in[2];
    const float* ln1w = (const float*)d_in[3];
    const float* ln1b = (const float*)d_in[4];
    const float* qkvw = (const float*)d_in[5];
    const float* qkvb = (const float*)d_in[6];
    const float* projw = (const float*)d_in[7];
    const float* projb = (const float*)d_in[8];
    const float* ln2w = (const float*)d_in[9];
    const float* ln2b = (const float*)d_in[10];
    const float* fcw = (const float*)d_in[11];
    const float* fcb = (const float*)d_in[12];
    const float* fcpw = (const float*)d_in[13];
    const float* fcpb = (const float*)d_in[14];
    const float* lnfw = (const float*)d_in[15];
    const float* lnfb = (const float*)d_in[16];

    char* p = (char*)d_ws;
    float* h = (float*)p;     p += (size_t)Mc * Dc * 4;      // f32 [M][D]
    hbf16* qkv = (hbf16*)p;   p += (size_t)Mc * 3 * Dc * 2;  // bf16 [M][3D]
    hbf16* a = (hbf16*)p;     p += (size_t)Mc * Dc * 2;      // bf16 [M][D]
    hbf16* y = (hbf16*)p;     p += (size_t)Mc * Dc * 2;      // bf16 [M][D]
    hbf16* mlp = (hbf16*)p;   p += (size_t)Mc * 4 * Dc * 2;  // bf16 [M][4D]
    hbf16* wte_b = (hbf16*)p; p += (size_t)Vpad * Dc * 2;    // [50304][768]
    hbf16* wtr = (hbf16*)p;                                  // transposed weights
    size_t used = (size_t)((char*)wtr - (char*)d_ws);
    bool all_mode = (ws_size - used) >= (size_t)Lc * SZL * 2;

    embed_kernel<<<(Mc * Dc + 255) / 256, 256, 0, stream>>>(x, wte, wpe, h);
    convert_wte<<<((size_t)Vpad * Dc / 4 + 255) / 256, 256, 0, stream>>>(wte, wte_b);

    if (all_mode) {
        transpose4_kernel<<<dim3(6912, Lc), 256, 0, stream>>>(
            qkvw, projw, fcw, fcpw,
            wtr, wtr + SZ_Q, wtr + SZ_Q + SZ_P, wtr + SZ_Q + SZ_P + SZ_F);
    }

    for (int l = 0; l < Lc; l++) {
        hbf16* base = wtr + (all_mode ? (size_t)l * SZL : 0);
        hbf16* wq_t = base;
        hbf16* wp_t = base + SZ_Q;
        hbf16* wf_t = base + SZ_Q + SZ_P;
        hbf16* wfp_t = base + SZ_Q + SZ_P + SZ_F;
        if (!all_mode) {
            transpose4_kernel<<<dim3(6912, 1), 256, 0, stream>>>(
                qkvw + (size_t)l * SZ_Q, projw + (size_t)l * SZ_P,
                fcw + (size_t)l * SZ_F, fcpw + (size_t)l * SZ_FP,
                wq_t, wp_t, wf_t, wfp_t);
        }

        ln_kernel<<<Mc / 4, 256, 0, stream>>>(h, ln1w + (size_t)l * Dc, ln1b + (size_t)l * Dc, a);
        mm_kernel<0, true, 128><<<dim3(3 * Dc / 128, Mc / 128), 256, 0, stream>>>(
            a, wq_t, qkvb + (size_t)l * 3 * Dc, nullptr, qkv, Mc, 3 * Dc, Dc);
        fattn_kernel<<<dim3(Tc / 64, Hc, Bc), 256, 0, stream>>>(qkv, y);
        mm_kernel<1, false, 64><<<dim3(Dc / 64, Mc / 128), 256, 0, stream>>>(
            y, wp_t, projb + (size_t)l * Dc, h, h, Mc, Dc, Dc);
        ln_kernel<<<Mc / 4, 256, 0, stream>>>(h, ln2w + (size_t)l * Dc, ln2b + (size_t)l * Dc, a);
        mm_kernel<2, true, 128><<<dim3(4 * Dc / 128, Mc / 128), 256, 0, stream>>>(
            a, wf_t, fcb + (size_t)l * 4 * Dc, nullptr, mlp, Mc, 4 * Dc, Dc);
        mm_kernel<1, false, 64><<<dim3(Dc / 64, Mc / 128), 256, 0, stream>>>(
            mlp, wfp_t, fcpb + (size_t)l * Dc, h, h, Mc, Dc, 4 * Dc);
    }

    ln_kernel<<<Mc / 4, 256, 0, stream>>>(h, lnfw, lnfb, a);
    mm2_kernel<<<dim3(Vpad / 128, Mc / 256), 512, 0, stream>>>(
        a, wte_b, (float*)d_out, Mc, Vc, Dc);
}